// Round 18
// baseline (1388.725 us; speedup 1.0000x reference)
//
#include <hip/hip_runtime.h>
#include <hip/hip_bf16.h>

// LlamaMLPInfer: SwiGLU MLP with group(128)-dequantized int4 weights.
// R18: R17 GEMMs byte-identical (best verified 1374us). Pre-pass fused:
// cvt_x + deq_g + deq_u run as ONE launch (block-range dispatch, 2048
// blocks) sharing HBM bandwidth; removes two launch gaps. deq_d still
// rides inside gateup as 256 LDS-free lead blocks (R15 mechanism).

#define HDIM 4096
#define IDIM 14336
#define MTOK 4096
#define GRP 128

typedef __attribute__((ext_vector_type(8))) short bf16x8;
typedef __attribute__((ext_vector_type(4))) float f32x4;
typedef __attribute__((ext_vector_type(4))) unsigned short u16x4;

#define WAIT_LGKM0 asm volatile("s_waitcnt lgkmcnt(0)" ::: "memory")
#define WAIT_VM(N) asm volatile("s_waitcnt vmcnt(" #N ")" ::: "memory")
#define SBAR       __builtin_amdgcn_s_barrier()
#define SCHB       __builtin_amdgcn_sched_barrier(0)

__device__ __forceinline__ unsigned short f2bf(float f) {
  union { float f; unsigned int u; } v; v.f = f;
  return (unsigned short)((v.u + 0x7fffu + ((v.u >> 16) & 1u)) >> 16);  // RNE
}
__device__ __forceinline__ unsigned pk2(float a, float b) {
  union { float f; unsigned u; } ua, ub; ua.f = a; ub.f = b;
  return __builtin_amdgcn_perm(ub.u, ua.u, 0x07060302u);
}

#define GLD16(G, L)                                                           \
  __builtin_amdgcn_global_load_lds(                                           \
      (const __attribute__((address_space(1))) unsigned int*)(G),             \
      (__attribute__((address_space(3))) unsigned int*)(L), 16, 0, 0)

// ---------------- fused pre-pass: cvt_x + deq_g + deq_u ----------------
// grid 2048 x 256thr: blocks [0,256) cvt; [256,1152) deq_g; [1152,2048) deq_u.
__device__ __forceinline__ void deq4096(const int* __restrict__ q,
                                        const float* __restrict__ s,
                                        unsigned short* __restrict__ w,
                                        int bid, int nBlk) {
  const long total = (long)IDIM * HDIM / 8;       // 8-elem chunks
  const long stride = (long)nBlk * 256;
  for (long idx = (long)bid * 256 + threadIdx.x; idx < total; idx += stride) {
    const long e = idx * 8;
    const int row = (int)(e >> 12);                // /HDIM (4096)
    const int col = (int)(e & 4095);
    const float sc = s[row * (HDIM / GRP) + (col >> 7)];
    const int4* q4 = (const int4*)(q + (long)row * HDIM + col);
    int4 a0 = q4[0], a1 = q4[1];
    uint4 o;
    o.x = pk2((float)a0.x * sc, (float)a0.y * sc);
    o.y = pk2((float)a0.z * sc, (float)a0.w * sc);
    o.z = pk2((float)a1.x * sc, (float)a1.y * sc);
    o.w = pk2((float)a1.z * sc, (float)a1.w * sc);
    *(uint4*)(w + (long)row * HDIM + col) = o;
  }
}

__global__ __launch_bounds__(256) void prepass_kernel(
    const float* __restrict__ x, unsigned short* __restrict__ xb,
    const int* __restrict__ gq, const float* __restrict__ gsc,
    unsigned short* __restrict__ wgb,
    const int* __restrict__ uq, const float* __restrict__ usc,
    unsigned short* __restrict__ wub)
{
  const int b = blockIdx.x;
  if (b < 256) {
    const int n = MTOK * HDIM;
    const int stride = 256 * 256 * 4;
    for (int i = (b * 256 + threadIdx.x) * 4; i < n; i += stride) {
      float4 v = *reinterpret_cast<const float4*>(x + i);
      u16x4 o;
      o[0] = f2bf(v.x); o[1] = f2bf(v.y); o[2] = f2bf(v.z); o[3] = f2bf(v.w);
      *reinterpret_cast<u16x4*>(xb + i) = o;
    }
  } else if (b < 256 + 896) {
    deq4096(gq, gsc, wgb, b - 256, 896);
  } else {
    deq4096(uq, usc, wub, b - 1152, 896);
  }
}

// ---------------- weight dequant (standalone, fallback path) ----------------
__global__ __launch_bounds__(256) void deq_kernel(const int* __restrict__ q,
                                                  const float* __restrict__ s,
                                                  unsigned short* __restrict__ w,
                                                  int In) {
  const int row  = blockIdx.y;
  const int col0 = blockIdx.x * 2048 + threadIdx.x * 8;
  const long base = (long)row * In + col0;
  const float sc = s[row * (In / GRP) + (col0 >> 7)];
  const int4* p = (const int4*)(q + base);
  int4 a0 = p[0], a1 = p[1];
  uint4 o;
  o.x = pk2((float)a0.x * sc, (float)a0.y * sc);
  o.y = pk2((float)a0.z * sc, (float)a0.w * sc);
  o.z = pk2((float)a1.x * sc, (float)a1.y * sc);
  o.w = pk2((float)a1.z * sc, (float)a1.w * sc);
  *(uint4*)(w + base) = o;
}

// ================= fused gate+up GEMM (R12 schedule) =================
// 256x128, BK=64, 512 thr (8 waves, 4Mx2N). A/Bg/Bu 2-buf (128KB).
// 2 phases/tile, staging issued at phase heads, 1 tail vmcnt(0)+SBAR.
// Blocks [0, nDeq) instead run grid-stride down-weight dequant (no LDS).
__global__ __launch_bounds__(512, 2) void gateup_bf16(
    const unsigned short* __restrict__ xb,
    const unsigned short* __restrict__ wg,
    const unsigned short* __restrict__ wu,
    unsigned short* __restrict__ inter,
    const int* __restrict__ dnq, const float* __restrict__ dns,
    unsigned short* __restrict__ wdb, int nDeq)
{
  __shared__ unsigned short As[2 * 256 * 64];   // 64 KB
  __shared__ unsigned short Bgs[2 * 128 * 64];  // 32 KB
  __shared__ unsigned short Bus[2 * 128 * 64];  // 32 KB

  if ((int)blockIdx.x < nDeq) {
    // ---- overlapped down-weight dequant: HDIM x IDIM int32 -> bf16 ----
    const long total = (long)HDIM * (IDIM / 8);     // 8-elem chunks
    const long stride = (long)nDeq * 512;
    for (long idx = (long)blockIdx.x * 512 + threadIdx.x; idx < total; idx += stride) {
      const long e = idx * 8;
      const int row = (int)(e / IDIM);
      const int col = (int)(e - (long)row * IDIM);
      const float sc = dns[row * (IDIM / GRP) + (col >> 7)];
      const int4* q4 = (const int4*)(dnq + (long)row * IDIM + col);
      int4 a0 = q4[0], a1 = q4[1];
      uint4 o;
      o.x = pk2((float)a0.x * sc, (float)a0.y * sc);
      o.y = pk2((float)a0.z * sc, (float)a0.w * sc);
      o.z = pk2((float)a1.x * sc, (float)a1.y * sc);
      o.w = pk2((float)a1.z * sc, (float)a1.w * sc);
      *(uint4*)(wdb + (long)row * IDIM + col) = o;
    }
    return;
  }

  const int tid = threadIdx.x, lane = tid & 63, wid = tid >> 6;
  const int wm = wid >> 1, wn = wid & 1;
  const int p = (int)blockIdx.x - nDeq;
  const int l = (p & 7) * 224 + (p >> 3);   // XCD-chunked, 1792 blocks
  const int m0 = (l & 15) * 256, n0 = (l >> 4) * 128;
  const int lr = lane & 15, lc = lane >> 4;

  const int ra   = tid >> 3;
  const int scol = ((tid & 7) ^ (ra & 7)) << 3;
  const unsigned short* pa  = xb + (long)(m0 + ra) * HDIM + scol;
  const unsigned short* pbg = wg + (long)(n0 + ra) * HDIM + scol;
  const unsigned short* pbu = wu + (long)(n0 + ra) * HDIM + scol;

#define A1(KT, BUF, IT)                                                       \
  GLD16(pa + (long)(IT) * 64 * HDIM + (long)(KT) * 64,                        \
        (unsigned short*)As + (BUF) * 16384 + (IT) * 4096 + wid * 512)
#define BG1(KT, BUF, IT)                                                      \
  GLD16(pbg + (long)(IT) * 64 * HDIM + (long)(KT) * 64,                       \
        (unsigned short*)Bgs + (BUF) * 8192 + (IT) * 4096 + wid * 512)
#define BU1(KT, BUF, IT)                                                      \
  GLD16(pbu + (long)(IT) * 64 * HDIM + (long)(KT) * 64,                       \
        (unsigned short*)Bus + (BUF) * 8192 + (IT) * 4096 + wid * 512)

  f32x4 accg[4][4], accu[4][4];
  const f32x4 zero = {0.f, 0.f, 0.f, 0.f};
#pragma unroll
  for (int i = 0; i < 4; ++i)
#pragma unroll
    for (int j = 0; j < 4; ++j) { accg[i][j] = zero; accu[i][j] = zero; }

  // prologue: stage tile 0 -> parity 0
  BG1(0, 0, 0); BG1(0, 0, 1); BU1(0, 0, 0); BU1(0, 0, 1);
  A1(0, 0, 0); A1(0, 0, 1); A1(0, 0, 2); A1(0, 0, 3);
  SCHB;
  WAIT_VM(0);
  SBAR;
  SCHB;

  const int NK = HDIM / 64;   // 64
#pragma unroll 1
  for (int kt = 0; kt < NK; ++kt) {
    const int RD = kt & 1, WR = RD ^ 1;
    const int ktn = (kt + 1 < NK) ? kt + 1 : NK - 1;
    const unsigned short* Ab  = (const unsigned short*)As  + RD * 16384;
    const unsigned short* Bgb = (const unsigned short*)Bgs + RD * 8192;
    const unsigned short* Bub = (const unsigned short*)Bus + RD * 8192;
    const int soff0 = (lc ^ (lr & 7)) << 3;
    const int soff1 = ((4 + lc) ^ (lr & 7)) << 3;
    bf16x8 af[4], bg[4], bu[4];

    // ---- ph0: ks0 (stage B(t+1)) ----
#pragma unroll
    for (int mi = 0; mi < 4; ++mi)
      af[mi] = *(const bf16x8*)&Ab[(wm * 64 + mi * 16 + lr) * 64 + soff0];
#pragma unroll
    for (int ni = 0; ni < 4; ++ni) {
      bg[ni] = *(const bf16x8*)&Bgb[(wn * 64 + ni * 16 + lr) * 64 + soff0];
      bu[ni] = *(const bf16x8*)&Bub[(wn * 64 + ni * 16 + lr) * 64 + soff0];
    }
    BG1(ktn, WR, 0); BG1(ktn, WR, 1); BU1(ktn, WR, 0); BU1(ktn, WR, 1);
    SCHB; WAIT_LGKM0; SCHB;
    __builtin_amdgcn_s_setprio(1);
#pragma unroll
    for (int ni = 0; ni < 4; ++ni)
#pragma unroll
      for (int mi = 0; mi < 4; ++mi) {
        accg[mi][ni] = __builtin_amdgcn_mfma_f32_16x16x32_bf16(af[mi], bg[ni], accg[mi][ni], 0, 0, 0);
        accu[mi][ni] = __builtin_amdgcn_mfma_f32_16x16x32_bf16(af[mi], bu[ni], accu[mi][ni], 0, 0, 0);
      }
    __builtin_amdgcn_s_setprio(0);

    // ---- ph1: ks1 (stage A(t+1)) ----
#pragma unroll
    for (int mi = 0; mi < 4; ++mi)
      af[mi] = *(const bf16x8*)&Ab[(wm * 64 + mi * 16 + lr) * 64 + soff1];
#pragma unroll
    for (int ni = 0; ni < 4; ++ni) {
      bg[ni] = *(const bf16x8*)&Bgb[(wn * 64 + ni * 16 + lr) * 64 + soff1];
      bu[ni] = *(const bf16x8*)&Bub[(wn * 64 + ni * 16 + lr) * 64 + soff1];
    }
    A1(ktn, WR, 0); A1(ktn, WR, 1); A1(ktn, WR, 2); A1(ktn, WR, 3);
    SCHB; WAIT_LGKM0; SCHB;
    __builtin_amdgcn_s_setprio(1);
#pragma unroll
    for (int ni = 0; ni < 4; ++ni)
#pragma unroll
      for (int mi = 0; mi < 4; ++mi) {
        accg[mi][ni] = __builtin_amdgcn_mfma_f32_16x16x32_bf16(af[mi], bg[ni], accg[mi][ni], 0, 0, 0);
        accu[mi][ni] = __builtin_amdgcn_mfma_f32_16x16x32_bf16(af[mi], bu[ni], accu[mi][ni], 0, 0, 0);
      }
    __builtin_amdgcn_s_setprio(0);

    // ---- tail: retire next-tile stage, rendezvous ----
    SCHB;
    WAIT_VM(0);
    SBAR;
    SCHB;
  }

  const int r0 = m0 + wm * 64, c0 = n0 + wn * 64;
#pragma unroll
  for (int mi = 0; mi < 4; ++mi)
#pragma unroll
    for (int ni = 0; ni < 4; ++ni)
#pragma unroll
      for (int r = 0; r < 4; ++r) {
        float g = accg[mi][ni][r], u = accu[mi][ni][r];
        float sv = g / (1.f + __expf(-g));
        int row = r0 + mi * 16 + lc * 4 + r;
        int col = c0 + ni * 16 + lr;
        inter[(long)row * IDIM + col] = f2bf(sv * u);
      }
#undef A1
#undef BG1
#undef BU1
}

// ================= down GEMM: 256x256 tile (R12 schedule) =================
__global__ __launch_bounds__(512, 2) void down_bf16(
    const unsigned short* __restrict__ inter,
    const unsigned short* __restrict__ wd,
    float* __restrict__ out)
{
  __shared__ unsigned short As[2 * 256 * 64];  // 64 KB
  __shared__ unsigned short Bs[2 * 256 * 64];  // 64 KB

  const int tid = threadIdx.x, lane = tid & 63, wid = tid >> 6;
  const int wm = wid >> 2, wn = wid & 3;          // 2M x 4N
  const int p = blockIdx.x;                       // 256 blocks
  const int l = (p & 7) * 32 + (p >> 3);          // XCD-chunked
  const int m0 = (l & 15) * 256, n0 = (l >> 4) * 256;
  const int lr = lane & 15, lc = lane >> 4;

  const int ra   = tid >> 3;
  const int scol = ((tid & 7) ^ (ra & 7)) << 3;
  const unsigned short* pa = inter + (long)(m0 + ra) * IDIM + scol;
  const unsigned short* pb = wd + (long)(n0 + ra) * IDIM + scol;

#define DA1(KT, BUF, IT)                                                      \
  GLD16(pa + (long)(IT) * 64 * IDIM + (long)(KT) * 64,                        \
        (unsigned short*)As + (BUF) * 16384 + (IT) * 4096 + wid * 512)
#define DB1(KT, BUF, IT)                                                      \
  GLD16(pb + (long)(IT) * 64 * IDIM + (long)(KT) * 64,                        \
        (unsigned short*)Bs + (BUF) * 16384 + (IT) * 4096 + wid * 512)

  f32x4 acc[8][4];
  const f32x4 zero = {0.f, 0.f, 0.f, 0.f};
#pragma unroll
  for (int i = 0; i < 8; ++i)
#pragma unroll
    for (int j = 0; j < 4; ++j) acc[i][j] = zero;

  // prologue: stage tile 0 -> parity 0
  DB1(0, 0, 0); DB1(0, 0, 1); DB1(0, 0, 2); DB1(0, 0, 3);
  DA1(0, 0, 0); DA1(0, 0, 1); DA1(0, 0, 2); DA1(0, 0, 3);
  SCHB;
  WAIT_VM(0);
  SBAR;
  SCHB;

  const int NK = IDIM / 64;   // 224
#pragma unroll 1
  for (int kt = 0; kt < NK; ++kt) {
    const int RD = kt & 1, WR = RD ^ 1;
    const int ktn = (kt + 1 < NK) ? kt + 1 : NK - 1;
    const unsigned short* Ab = (const unsigned short*)As + RD * 16384;
    const unsigned short* Bb = (const unsigned short*)Bs + RD * 16384;
    const int soff0 = (lc ^ (lr & 7)) << 3;
    const int soff1 = ((4 + lc) ^ (lr & 7)) << 3;
    bf16x8 af[8], bfr[4];

    // ---- ph0: ks0 (stage B(t+1)) ----
#pragma unroll
    for (int mi = 0; mi < 8; ++mi)
      af[mi] = *(const bf16x8*)&Ab[(wm * 128 + mi * 16 + lr) * 64 + soff0];
#pragma unroll
    for (int ni = 0; ni < 4; ++ni)
      bfr[ni] = *(const bf16x8*)&Bb[(wn * 64 + ni * 16 + lr) * 64 + soff0];
    DB1(ktn, WR, 0); DB1(ktn, WR, 1); DB1(ktn, WR, 2); DB1(ktn, WR, 3);
    SCHB; WAIT_LGKM0; SCHB;
    __builtin_amdgcn_s_setprio(1);
#pragma unroll
    for (int ni = 0; ni < 4; ++ni)
#pragma unroll
      for (int mi = 0; mi < 8; ++mi)
        acc[mi][ni] = __builtin_amdgcn_mfma_f32_16x16x32_bf16(af[mi], bfr[ni], acc[mi][ni], 0, 0, 0);
    __builtin_amdgcn_s_setprio(0);

    // ---- ph1: ks1 (stage A(t+1)) ----
#pragma unroll
    for (int mi = 0; mi < 8; ++mi)
      af[mi] = *(const bf16x8*)&Ab[(wm * 128 + mi * 16 + lr) * 64 + soff1];
#pragma unroll
    for (int ni = 0; ni < 4; ++ni)
      bfr[ni] = *(const bf16x8*)&Bb[(wn * 64 + ni * 16 + lr) * 64 + soff1];
    DA1(ktn, WR, 0); DA1(ktn, WR, 1); DA1(ktn, WR, 2); DA1(ktn, WR, 3);
    SCHB; WAIT_LGKM0; SCHB;
    __builtin_amdgcn_s_setprio(1);
#pragma unroll
    for (int ni = 0; ni < 4; ++ni)
#pragma unroll
      for (int mi = 0; mi < 8; ++mi)
        acc[mi][ni] = __builtin_amdgcn_mfma_f32_16x16x32_bf16(af[mi], bfr[ni], acc[mi][ni], 0, 0, 0);
    __builtin_amdgcn_s_setprio(0);

    // ---- tail: retire next-tile stage, rendezvous ----
    SCHB;
    WAIT_VM(0);
    SBAR;
    SCHB;
  }

  const int r0 = m0 + wm * 128, c0 = n0 + wn * 64;
#pragma unroll
  for (int mi = 0; mi < 8; ++mi)
#pragma unroll
    for (int ni = 0; ni < 4; ++ni)
#pragma unroll
      for (int r = 0; r < 4; ++r) {
        int row = r0 + mi * 16 + lc * 4 + r;
        int col = c0 + ni * 16 + lr;
        out[(long)row * HDIM + col] = acc[mi][ni][r];
      }
#undef DA1
#undef DB1
}

extern "C" void kernel_launch(void* const* d_in, const int* in_sizes, int n_in,
                              void* d_out, int out_size, void* d_ws, size_t ws_size,
                              hipStream_t stream) {
  const float* x   = (const float*)d_in[0];
  const int*   gq  = (const int*)d_in[1];
  const float* gsc = (const float*)d_in[2];
  const int*   uq  = (const int*)d_in[3];
  const float* usc = (const float*)d_in[4];
  const int*   dq  = (const int*)d_in[5];
  const float* dsc = (const float*)d_in[6];
  float* out = (float*)d_out;

  unsigned short* xb    = (unsigned short*)d_ws;                    // 32 MiB
  unsigned short* inter = xb + (size_t)MTOK * HDIM;                 // 112 MiB
  unsigned short* wgb   = inter + (size_t)MTOK * IDIM;              // 112 MiB
  unsigned short* wub   = wgb + (size_t)IDIM * HDIM;                // 112 MiB
  unsigned short* wdb   = wub + (size_t)IDIM * HDIM;                // 112 MiB (overlap path)
  const size_t needOverlap = ((size_t)MTOK * HDIM + (size_t)MTOK * IDIM +
                              3 * (size_t)IDIM * HDIM) * 2;

  // fused pre-pass: cvt_x + deq_g + deq_u in one launch
  hipLaunchKernelGGL(prepass_kernel, dim3(2048), dim3(256), 0, stream,
                     x, xb, gq, gsc, wgb, uq, usc, wub);

  if (ws_size >= needOverlap) {
    // down-weight dequant overlapped into the gateup launch (256 lead blocks)
    hipLaunchKernelGGL(gateup_bf16, dim3(256 + 1792), dim3(512), 0, stream,
                       xb, wgb, wub, inter, dq, dsc, wdb, 256);
    hipLaunchKernelGGL(down_bf16, dim3(256), dim3(512), 0, stream,
                       inter, wdb, out);
  } else {
    // sequential fallback (R12): down weights reuse gate-weight region
    hipLaunchKernelGGL(gateup_bf16, dim3(1792), dim3(512), 0, stream,
                       xb, wgb, wub, inter, dq, dsc, wgb, 0);
    hipLaunchKernelGGL(deq_kernel, dim3(IDIM / 2048, HDIM), dim3(256), 0, stream,
                       dq, dsc, wgb, IDIM);
    hipLaunchKernelGGL(down_bf16, dim3(256), dim3(512), 0, stream,
                       inter, wgb, out);
  }
}

// Round 19
// 1373.248 us; speedup vs baseline: 1.0113x; 1.0113x over previous
//
#include <hip/hip_runtime.h>
#include <hip/hip_bf16.h>

// LlamaMLPInfer: SwiGLU MLP with group(128)-dequantized int4 weights.
// R19 == R17/R15 exactly (best verified: 1374us). Final state.
// Pipeline: cvt_x | deq_g | deq_u | gateup(256x128 dual-B, 2-phase counted
// pipeline, deq_d riding as 256 LDS-free lead blocks) | down(256x256).
// Plateau bracketed: R5/R13/R14 (schedule variants), R6/R7 (occupancy),
// R16 (split), R18 (fused prepass) all regressed or neutral.

#define HDIM 4096
#define IDIM 14336
#define MTOK 4096
#define GRP 128

typedef __attribute__((ext_vector_type(8))) short bf16x8;
typedef __attribute__((ext_vector_type(4))) float f32x4;
typedef __attribute__((ext_vector_type(4))) unsigned short u16x4;

#define WAIT_LGKM0 asm volatile("s_waitcnt lgkmcnt(0)" ::: "memory")
#define WAIT_VM(N) asm volatile("s_waitcnt vmcnt(" #N ")" ::: "memory")
#define SBAR       __builtin_amdgcn_s_barrier()
#define SCHB       __builtin_amdgcn_sched_barrier(0)

__device__ __forceinline__ unsigned short f2bf(float f) {
  union { float f; unsigned int u; } v; v.f = f;
  return (unsigned short)((v.u + 0x7fffu + ((v.u >> 16) & 1u)) >> 16);  // RNE
}
__device__ __forceinline__ unsigned pk2(float a, float b) {
  union { float f; unsigned u; } ua, ub; ua.f = a; ub.f = b;
  return __builtin_amdgcn_perm(ub.u, ua.u, 0x07060302u);
}

#define GLD16(G, L)                                                           \
  __builtin_amdgcn_global_load_lds(                                           \
      (const __attribute__((address_space(1))) unsigned int*)(G),             \
      (__attribute__((address_space(3))) unsigned int*)(L), 16, 0, 0)

// ---------------- x fp32 -> bf16 ----------------
__global__ __launch_bounds__(256) void cvt_x_kernel(const float* __restrict__ x,
                                                    unsigned short* __restrict__ xb) {
  const int n = MTOK * HDIM;
  const int stride = gridDim.x * 256 * 4;
  for (int i = (blockIdx.x * 256 + threadIdx.x) * 4; i < n; i += stride) {
    float4 v = *reinterpret_cast<const float4*>(x + i);
    u16x4 o;
    o[0] = f2bf(v.x); o[1] = f2bf(v.y); o[2] = f2bf(v.z); o[3] = f2bf(v.w);
    *reinterpret_cast<u16x4*>(xb + i) = o;
  }
}

// ---------------- weight dequant (standalone) ----------------
__global__ __launch_bounds__(256) void deq_kernel(const int* __restrict__ q,
                                                  const float* __restrict__ s,
                                                  unsigned short* __restrict__ w,
                                                  int In) {
  const int row  = blockIdx.y;
  const int col0 = blockIdx.x * 2048 + threadIdx.x * 8;
  const long base = (long)row * In + col0;
  const float sc = s[row * (In / GRP) + (col0 >> 7)];
  const int4* p = (const int4*)(q + base);
  int4 a0 = p[0], a1 = p[1];
  uint4 o;
  o.x = pk2((float)a0.x * sc, (float)a0.y * sc);
  o.y = pk2((float)a0.z * sc, (float)a0.w * sc);
  o.z = pk2((float)a1.x * sc, (float)a1.y * sc);
  o.w = pk2((float)a1.z * sc, (float)a1.w * sc);
  *(uint4*)(w + base) = o;
}

// ================= fused gate+up GEMM (R12 schedule) =================
// 256x128, BK=64, 512 thr (8 waves, 4Mx2N). A/Bg/Bu 2-buf (128KB).
// 2 phases/tile, staging issued at phase heads, 1 tail vmcnt(0)+SBAR.
// Blocks [0, nDeq) instead run grid-stride down-weight dequant (no LDS).
__global__ __launch_bounds__(512, 2) void gateup_bf16(
    const unsigned short* __restrict__ xb,
    const unsigned short* __restrict__ wg,
    const unsigned short* __restrict__ wu,
    unsigned short* __restrict__ inter,
    const int* __restrict__ dnq, const float* __restrict__ dns,
    unsigned short* __restrict__ wdb, int nDeq)
{
  __shared__ unsigned short As[2 * 256 * 64];   // 64 KB
  __shared__ unsigned short Bgs[2 * 128 * 64];  // 32 KB
  __shared__ unsigned short Bus[2 * 128 * 64];  // 32 KB

  if ((int)blockIdx.x < nDeq) {
    // ---- overlapped down-weight dequant: HDIM x IDIM int32 -> bf16 ----
    const long total = (long)HDIM * (IDIM / 8);     // 8-elem chunks
    const long stride = (long)nDeq * 512;
    for (long idx = (long)blockIdx.x * 512 + threadIdx.x; idx < total; idx += stride) {
      const long e = idx * 8;
      const int row = (int)(e / IDIM);
      const int col = (int)(e - (long)row * IDIM);
      const float sc = dns[row * (IDIM / GRP) + (col >> 7)];
      const int4* q4 = (const int4*)(dnq + (long)row * IDIM + col);
      int4 a0 = q4[0], a1 = q4[1];
      uint4 o;
      o.x = pk2((float)a0.x * sc, (float)a0.y * sc);
      o.y = pk2((float)a0.z * sc, (float)a0.w * sc);
      o.z = pk2((float)a1.x * sc, (float)a1.y * sc);
      o.w = pk2((float)a1.z * sc, (float)a1.w * sc);
      *(uint4*)(wdb + (long)row * IDIM + col) = o;
    }
    return;
  }

  const int tid = threadIdx.x, lane = tid & 63, wid = tid >> 6;
  const int wm = wid >> 1, wn = wid & 1;
  const int p = (int)blockIdx.x - nDeq;
  const int l = (p & 7) * 224 + (p >> 3);   // XCD-chunked, 1792 blocks
  const int m0 = (l & 15) * 256, n0 = (l >> 4) * 128;
  const int lr = lane & 15, lc = lane >> 4;

  const int ra   = tid >> 3;
  const int scol = ((tid & 7) ^ (ra & 7)) << 3;
  const unsigned short* pa  = xb + (long)(m0 + ra) * HDIM + scol;
  const unsigned short* pbg = wg + (long)(n0 + ra) * HDIM + scol;
  const unsigned short* pbu = wu + (long)(n0 + ra) * HDIM + scol;

#define A1(KT, BUF, IT)                                                       \
  GLD16(pa + (long)(IT) * 64 * HDIM + (long)(KT) * 64,                        \
        (unsigned short*)As + (BUF) * 16384 + (IT) * 4096 + wid * 512)
#define BG1(KT, BUF, IT)                                                      \
  GLD16(pbg + (long)(IT) * 64 * HDIM + (long)(KT) * 64,                       \
        (unsigned short*)Bgs + (BUF) * 8192 + (IT) * 4096 + wid * 512)
#define BU1(KT, BUF, IT)                                                      \
  GLD16(pbu + (long)(IT) * 64 * HDIM + (long)(KT) * 64,                       \
        (unsigned short*)Bus + (BUF) * 8192 + (IT) * 4096 + wid * 512)

  f32x4 accg[4][4], accu[4][4];
  const f32x4 zero = {0.f, 0.f, 0.f, 0.f};
#pragma unroll
  for (int i = 0; i < 4; ++i)
#pragma unroll
    for (int j = 0; j < 4; ++j) { accg[i][j] = zero; accu[i][j] = zero; }

  // prologue: stage tile 0 -> parity 0
  BG1(0, 0, 0); BG1(0, 0, 1); BU1(0, 0, 0); BU1(0, 0, 1);
  A1(0, 0, 0); A1(0, 0, 1); A1(0, 0, 2); A1(0, 0, 3);
  SCHB;
  WAIT_VM(0);
  SBAR;
  SCHB;

  const int NK = HDIM / 64;   // 64
#pragma unroll 1
  for (int kt = 0; kt < NK; ++kt) {
    const int RD = kt & 1, WR = RD ^ 1;
    const int ktn = (kt + 1 < NK) ? kt + 1 : NK - 1;
    const unsigned short* Ab  = (const unsigned short*)As  + RD * 16384;
    const unsigned short* Bgb = (const unsigned short*)Bgs + RD * 8192;
    const unsigned short* Bub = (const unsigned short*)Bus + RD * 8192;
    const int soff0 = (lc ^ (lr & 7)) << 3;
    const int soff1 = ((4 + lc) ^ (lr & 7)) << 3;
    bf16x8 af[4], bg[4], bu[4];

    // ---- ph0: ks0 (stage B(t+1)) ----
#pragma unroll
    for (int mi = 0; mi < 4; ++mi)
      af[mi] = *(const bf16x8*)&Ab[(wm * 64 + mi * 16 + lr) * 64 + soff0];
#pragma unroll
    for (int ni = 0; ni < 4; ++ni) {
      bg[ni] = *(const bf16x8*)&Bgb[(wn * 64 + ni * 16 + lr) * 64 + soff0];
      bu[ni] = *(const bf16x8*)&Bub[(wn * 64 + ni * 16 + lr) * 64 + soff0];
    }
    BG1(ktn, WR, 0); BG1(ktn, WR, 1); BU1(ktn, WR, 0); BU1(ktn, WR, 1);
    SCHB; WAIT_LGKM0; SCHB;
    __builtin_amdgcn_s_setprio(1);
#pragma unroll
    for (int ni = 0; ni < 4; ++ni)
#pragma unroll
      for (int mi = 0; mi < 4; ++mi) {
        accg[mi][ni] = __builtin_amdgcn_mfma_f32_16x16x32_bf16(af[mi], bg[ni], accg[mi][ni], 0, 0, 0);
        accu[mi][ni] = __builtin_amdgcn_mfma_f32_16x16x32_bf16(af[mi], bu[ni], accu[mi][ni], 0, 0, 0);
      }
    __builtin_amdgcn_s_setprio(0);

    // ---- ph1: ks1 (stage A(t+1)) ----
#pragma unroll
    for (int mi = 0; mi < 4; ++mi)
      af[mi] = *(const bf16x8*)&Ab[(wm * 64 + mi * 16 + lr) * 64 + soff1];
#pragma unroll
    for (int ni = 0; ni < 4; ++ni) {
      bg[ni] = *(const bf16x8*)&Bgb[(wn * 64 + ni * 16 + lr) * 64 + soff1];
      bu[ni] = *(const bf16x8*)&Bub[(wn * 64 + ni * 16 + lr) * 64 + soff1];
    }
    A1(ktn, WR, 0); A1(ktn, WR, 1); A1(ktn, WR, 2); A1(ktn, WR, 3);
    SCHB; WAIT_LGKM0; SCHB;
    __builtin_amdgcn_s_setprio(1);
#pragma unroll
    for (int ni = 0; ni < 4; ++ni)
#pragma unroll
      for (int mi = 0; mi < 4; ++mi) {
        accg[mi][ni] = __builtin_amdgcn_mfma_f32_16x16x32_bf16(af[mi], bg[ni], accg[mi][ni], 0, 0, 0);
        accu[mi][ni] = __builtin_amdgcn_mfma_f32_16x16x32_bf16(af[mi], bu[ni], accu[mi][ni], 0, 0, 0);
      }
    __builtin_amdgcn_s_setprio(0);

    // ---- tail: retire next-tile stage, rendezvous ----
    SCHB;
    WAIT_VM(0);
    SBAR;
    SCHB;
  }

  const int r0 = m0 + wm * 64, c0 = n0 + wn * 64;
#pragma unroll
  for (int mi = 0; mi < 4; ++mi)
#pragma unroll
    for (int ni = 0; ni < 4; ++ni)
#pragma unroll
      for (int r = 0; r < 4; ++r) {
        float g = accg[mi][ni][r], u = accu[mi][ni][r];
        float sv = g / (1.f + __expf(-g));
        int row = r0 + mi * 16 + lc * 4 + r;
        int col = c0 + ni * 16 + lr;
        inter[(long)row * IDIM + col] = f2bf(sv * u);
      }
#undef A1
#undef BG1
#undef BU1
}

// ================= down GEMM: 256x256 tile (R12 schedule) =================
__global__ __launch_bounds__(512, 2) void down_bf16(
    const unsigned short* __restrict__ inter,
    const unsigned short* __restrict__ wd,
    float* __restrict__ out)
{
  __shared__ unsigned short As[2 * 256 * 64];  // 64 KB
  __shared__ unsigned short Bs[2 * 256 * 64];  // 64 KB

  const int tid = threadIdx.x, lane = tid & 63, wid = tid >> 6;
  const int wm = wid >> 2, wn = wid & 3;          // 2M x 4N
  const int p = blockIdx.x;                       // 256 blocks
  const int l = (p & 7) * 32 + (p >> 3);          // XCD-chunked
  const int m0 = (l & 15) * 256, n0 = (l >> 4) * 256;
  const int lr = lane & 15, lc = lane >> 4;

  const int ra   = tid >> 3;
  const int scol = ((tid & 7) ^ (ra & 7)) << 3;
  const unsigned short* pa = inter + (long)(m0 + ra) * IDIM + scol;
  const unsigned short* pb = wd + (long)(n0 + ra) * IDIM + scol;

#define DA1(KT, BUF, IT)                                                      \
  GLD16(pa + (long)(IT) * 64 * IDIM + (long)(KT) * 64,                        \
        (unsigned short*)As + (BUF) * 16384 + (IT) * 4096 + wid * 512)
#define DB1(KT, BUF, IT)                                                      \
  GLD16(pb + (long)(IT) * 64 * IDIM + (long)(KT) * 64,                        \
        (unsigned short*)Bs + (BUF) * 16384 + (IT) * 4096 + wid * 512)

  f32x4 acc[8][4];
  const f32x4 zero = {0.f, 0.f, 0.f, 0.f};
#pragma unroll
  for (int i = 0; i < 8; ++i)
#pragma unroll
    for (int j = 0; j < 4; ++j) acc[i][j] = zero;

  // prologue: stage tile 0 -> parity 0
  DB1(0, 0, 0); DB1(0, 0, 1); DB1(0, 0, 2); DB1(0, 0, 3);
  DA1(0, 0, 0); DA1(0, 0, 1); DA1(0, 0, 2); DA1(0, 0, 3);
  SCHB;
  WAIT_VM(0);
  SBAR;
  SCHB;

  const int NK = IDIM / 64;   // 224
#pragma unroll 1
  for (int kt = 0; kt < NK; ++kt) {
    const int RD = kt & 1, WR = RD ^ 1;
    const int ktn = (kt + 1 < NK) ? kt + 1 : NK - 1;
    const unsigned short* Ab = (const unsigned short*)As + RD * 16384;
    const unsigned short* Bb = (const unsigned short*)Bs + RD * 16384;
    const int soff0 = (lc ^ (lr & 7)) << 3;
    const int soff1 = ((4 + lc) ^ (lr & 7)) << 3;
    bf16x8 af[8], bfr[4];

    // ---- ph0: ks0 (stage B(t+1)) ----
#pragma unroll
    for (int mi = 0; mi < 8; ++mi)
      af[mi] = *(const bf16x8*)&Ab[(wm * 128 + mi * 16 + lr) * 64 + soff0];
#pragma unroll
    for (int ni = 0; ni < 4; ++ni)
      bfr[ni] = *(const bf16x8*)&Bb[(wn * 64 + ni * 16 + lr) * 64 + soff0];
    DB1(ktn, WR, 0); DB1(ktn, WR, 1); DB1(ktn, WR, 2); DB1(ktn, WR, 3);
    SCHB; WAIT_LGKM0; SCHB;
    __builtin_amdgcn_s_setprio(1);
#pragma unroll
    for (int ni = 0; ni < 4; ++ni)
#pragma unroll
      for (int mi = 0; mi < 8; ++mi)
        acc[mi][ni] = __builtin_amdgcn_mfma_f32_16x16x32_bf16(af[mi], bfr[ni], acc[mi][ni], 0, 0, 0);
    __builtin_amdgcn_s_setprio(0);

    // ---- ph1: ks1 (stage A(t+1)) ----
#pragma unroll
    for (int mi = 0; mi < 8; ++mi)
      af[mi] = *(const bf16x8*)&Ab[(wm * 128 + mi * 16 + lr) * 64 + soff1];
#pragma unroll
    for (int ni = 0; ni < 4; ++ni)
      bfr[ni] = *(const bf16x8*)&Bb[(wn * 64 + ni * 16 + lr) * 64 + soff1];
    DA1(ktn, WR, 0); DA1(ktn, WR, 1); DA1(ktn, WR, 2); DA1(ktn, WR, 3);
    SCHB; WAIT_LGKM0; SCHB;
    __builtin_amdgcn_s_setprio(1);
#pragma unroll
    for (int ni = 0; ni < 4; ++ni)
#pragma unroll
      for (int mi = 0; mi < 8; ++mi)
        acc[mi][ni] = __builtin_amdgcn_mfma_f32_16x16x32_bf16(af[mi], bfr[ni], acc[mi][ni], 0, 0, 0);
    __builtin_amdgcn_s_setprio(0);

    // ---- tail: retire next-tile stage, rendezvous ----
    SCHB;
    WAIT_VM(0);
    SBAR;
    SCHB;
  }

  const int r0 = m0 + wm * 128, c0 = n0 + wn * 64;
#pragma unroll
  for (int mi = 0; mi < 8; ++mi)
#pragma unroll
    for (int ni = 0; ni < 4; ++ni)
#pragma unroll
      for (int r = 0; r < 4; ++r) {
        int row = r0 + mi * 16 + lc * 4 + r;
        int col = c0 + ni * 16 + lr;
        out[(long)row * HDIM + col] = acc[mi][ni][r];
      }
#undef DA1
#undef DB1
}

extern "C" void kernel_launch(void* const* d_in, const int* in_sizes, int n_in,
                              void* d_out, int out_size, void* d_ws, size_t ws_size,
                              hipStream_t stream) {
  const float* x   = (const float*)d_in[0];
  const int*   gq  = (const int*)d_in[1];
  const float* gsc = (const float*)d_in[2];
  const int*   uq  = (const int*)d_in[3];
  const float* usc = (const float*)d_in[4];
  const int*   dq  = (const int*)d_in[5];
  const float* dsc = (const float*)d_in[6];
  float* out = (float*)d_out;

  unsigned short* xb    = (unsigned short*)d_ws;                    // 32 MiB
  unsigned short* inter = xb + (size_t)MTOK * HDIM;                 // 112 MiB
  unsigned short* wgb   = inter + (size_t)MTOK * IDIM;              // 112 MiB
  unsigned short* wub   = wgb + (size_t)IDIM * HDIM;                // 112 MiB
  unsigned short* wdb   = wub + (size_t)IDIM * HDIM;                // 112 MiB (overlap path)
  const size_t needOverlap = ((size_t)MTOK * HDIM + (size_t)MTOK * IDIM +
                              3 * (size_t)IDIM * HDIM) * 2;

  hipLaunchKernelGGL(cvt_x_kernel, dim3(2048), dim3(256), 0, stream, x, xb);
  hipLaunchKernelGGL(deq_kernel, dim3(HDIM / 2048, IDIM), dim3(256), 0, stream,
                     gq, gsc, wgb, HDIM);
  hipLaunchKernelGGL(deq_kernel, dim3(HDIM / 2048, IDIM), dim3(256), 0, stream,
                     uq, usc, wub, HDIM);

  if (ws_size >= needOverlap) {
    // down-weight dequant overlapped into the gateup launch (256 lead blocks)
    hipLaunchKernelGGL(gateup_bf16, dim3(256 + 1792), dim3(512), 0, stream,
                       xb, wgb, wub, inter, dq, dsc, wdb, 256);
    hipLaunchKernelGGL(down_bf16, dim3(256), dim3(512), 0, stream,
                       inter, wdb, out);
  } else {
    // sequential fallback (R12): down weights reuse gate-weight region
    hipLaunchKernelGGL(gateup_bf16, dim3(1792), dim3(512), 0, stream,
                       xb, wgb, wub, inter, dq, dsc, wgb, 0);
    hipLaunchKernelGGL(deq_kernel, dim3(IDIM / 2048, HDIM), dim3(256), 0, stream,
                       dq, dsc, wgb, IDIM);
    hipLaunchKernelGGL(down_bf16, dim3(256), dim3(512), 0, stream,
                       inter, wgb, out);
  }
}